// Round 2
// baseline (7372.231 us; speedup 1.0000x reference)
//
#include <hip/hip_runtime.h>
#include <hip/hip_bf16.h>

#define SEQ 512
#define NB  64
#define HF  1024

typedef float f32x4 __attribute__((ext_vector_type(4)));
typedef short s16x8 __attribute__((ext_vector_type(8)));
typedef short s16x4 __attribute__((ext_vector_type(4)));

__device__ __forceinline__ unsigned short bf16_rne(float f) {
    unsigned u = __builtin_bit_cast(unsigned, f);
    u += 0x7FFFu + ((u >> 16) & 1u);
    return (unsigned short)(u >> 16);
}

// split f = hi + lo (hi = truncated bf16, lo = rne bf16 of exact remainder)
__device__ __forceinline__ void bf16_split(float f, short& hi, short& lo) {
    unsigned u = __builtin_bit_cast(unsigned, f);
    hi = (short)(u >> 16);
    float fh = __builtin_bit_cast(float, u & 0xFFFF0000u);
    lo = (short)bf16_rne(f - fh);
}

__device__ __forceinline__ f32x4 mfma16(s16x8 a, s16x8 b, f32x4 c) {
    return __builtin_amdgcn_mfma_f32_16x16x32_bf16(a, b, c, 0, 0, 0);
}

// ---------------------------------------------------------------------------
// Phase 1: Ux = X @ U^T + U_b   (written into d_out, layout [B,S,H] = [32768,1024])
// 128x128 tiles, K-step 32, split-bf16 (3-term) MFMA.
// ---------------------------------------------------------------------------
__global__ __launch_bounds__(256, 2) void ux_gemm(const float* __restrict__ X,
                                                  const float* __restrict__ U,
                                                  const float* __restrict__ Ubias,
                                                  float* __restrict__ out) {
    __shared__ short Ah[128][40], Al[128][40], Bh[128][40], Bl[128][40];

    int bid = blockIdx.x;                    // 2048 = 256 m-tiles * 8 n-tiles
    int swz = (bid & 7) * 256 + (bid >> 3);  // XCD-contiguous chunks (2048 % 8 == 0)
    int tm = swz & 255;
    int tn = swz >> 8;

    int tid  = threadIdx.x;
    int lrow = tid >> 3;           // 0..31
    int lcol = (tid & 7) << 2;     // 0,4,..,28

    int wave = tid >> 6, lane = tid & 63;
    int wr = (wave >> 1) << 6;     // wave row offset (0/64)
    int wc = (wave & 1) << 6;      // wave col offset (0/64)
    int fr = lane & 15, fkq = lane >> 4;

    const float* Xb = X + (size_t)tm * 128 * HF;
    const float* Ub = U + (size_t)tn * 128 * HF;

    f32x4 acc[4][4];
    #pragma unroll
    for (int mi = 0; mi < 4; ++mi)
        #pragma unroll
        for (int ni = 0; ni < 4; ++ni)
            acc[mi][ni] = f32x4{0.f, 0.f, 0.f, 0.f};

    for (int kt = 0; kt < HF; kt += 32) {
        __syncthreads();
        #pragma unroll
        for (int p = 0; p < 4; ++p) {
            int r = lrow + (p << 5);
            f32x4 xv = *(const f32x4*)(Xb + (size_t)r * HF + kt + lcol);
            f32x4 uv = *(const f32x4*)(Ub + (size_t)r * HF + kt + lcol);
            s16x4 xh, xl, uh, ul;
            #pragma unroll
            for (int e = 0; e < 4; ++e) {
                short h_, l_;
                bf16_split(xv[e], h_, l_); xh[e] = h_; xl[e] = l_;
                bf16_split(uv[e], h_, l_); uh[e] = h_; ul[e] = l_;
            }
            *(s16x4*)&Ah[r][lcol] = xh;
            *(s16x4*)&Al[r][lcol] = xl;
            *(s16x4*)&Bh[r][lcol] = uh;
            *(s16x4*)&Bl[r][lcol] = ul;
        }
        __syncthreads();

        s16x8 afh[4], afl[4], bfh[4], bfl[4];
        #pragma unroll
        for (int mi = 0; mi < 4; ++mi) {
            afh[mi] = *(const s16x8*)&Ah[wr + mi * 16 + fr][fkq * 8];
            afl[mi] = *(const s16x8*)&Al[wr + mi * 16 + fr][fkq * 8];
            bfh[mi] = *(const s16x8*)&Bh[wc + mi * 16 + fr][fkq * 8];
            bfl[mi] = *(const s16x8*)&Bl[wc + mi * 16 + fr][fkq * 8];
        }
        #pragma unroll
        for (int mi = 0; mi < 4; ++mi)
            #pragma unroll
            for (int ni = 0; ni < 4; ++ni)
                acc[mi][ni] = mfma16(afh[mi], bfh[ni], acc[mi][ni]);
        #pragma unroll
        for (int mi = 0; mi < 4; ++mi)
            #pragma unroll
            for (int ni = 0; ni < 4; ++ni)
                acc[mi][ni] = mfma16(afh[mi], bfl[ni], acc[mi][ni]);
        #pragma unroll
        for (int mi = 0; mi < 4; ++mi)
            #pragma unroll
            for (int ni = 0; ni < 4; ++ni)
                acc[mi][ni] = mfma16(afl[mi], bfh[ni], acc[mi][ni]);
    }

    // epilogue: C/D layout col = lane&15, row = (lane>>4)*4 + i  [m89]
    #pragma unroll
    for (int ni = 0; ni < 4; ++ni) {
        int col = tn * 128 + wc + ni * 16 + fr;
        float ub = Ubias[col];
        #pragma unroll
        for (int mi = 0; mi < 4; ++mi) {
            #pragma unroll
            for (int i = 0; i < 4; ++i) {
                int row = tm * 128 + wr + mi * 16 + fkq * 4 + i;
                out[(size_t)row * HF + col] = acc[mi][ni][i] + ub;
            }
        }
    }
}

// ---------------------------------------------------------------------------
// Phase 2: 512 sequential steps  h = tanh(Ux_t + h@W^T + W_b)
// 64 persistent WGs (4 batch-tiles x 16 WGs). Each wave owns 16 output cols
// with its W slice (split bf16) in 256 VGPRs. Per-btile flag sync via
// agent-scope atomics; h double-buffered (split bf16) in workspace.
// Ux read in-place from d_out, overwritten with h.
// ---------------------------------------------------------------------------
__global__ __launch_bounds__(256, 1) void rnn_scan(const float* __restrict__ Ww,
                                                   const float* __restrict__ Wb,
                                                   float* __restrict__ out,
                                                   short* __restrict__ hb_hi,
                                                   short* __restrict__ hb_lo,
                                                   unsigned int* __restrict__ cnt) {
    int bid   = blockIdx.x;        // 64
    int btile = bid >> 4;          // 0..3  (16 batches each)
    int tid   = threadIdx.x;
    int wave  = tid >> 6, lane = tid & 63;
    int j0    = ((bid & 15) * 4 + wave) << 4;   // output col slice base
    int fr    = lane & 15, fkq = lane >> 4;
    int j     = j0 + fr;           // this lane's output column (B-frag col / D col)
    int b0    = btile << 4;

    // --- prologue: W fragments (rows j of W_w), split hi/lo, held in VGPRs ---
    s16x8 wh[32], wl[32];
    {
        const float* wp = Ww + (size_t)j * HF + fkq * 8;
        #pragma unroll
        for (int kt = 0; kt < 32; ++kt) {
            f32x4 a = *(const f32x4*)(wp + kt * 32);
            f32x4 b = *(const f32x4*)(wp + kt * 32 + 4);
            s16x8 hi, lo;
            #pragma unroll
            for (int e = 0; e < 4; ++e) {
                short h_, l_;
                bf16_split(a[e], h_, l_); hi[e]     = h_; lo[e]     = l_;
                bf16_split(b[e], h_, l_); hi[e + 4] = h_; lo[e + 4] = l_;
            }
            wh[kt] = hi; wl[kt] = lo;
        }
    }
    float wb = Wb[j];

    unsigned int* mycnt = cnt + btile * SEQ;

    #pragma unroll 1
    for (int t = 0; t < SEQ; ++t) {
        // issue Ux loads early (independent of the flag)
        float ux[4];
        #pragma unroll
        for (int i = 0; i < 4; ++i) {
            int r = b0 + fkq * 4 + i;
            ux[i] = out[((size_t)r * SEQ + t) * HF + j];
        }

        f32x4 sum = {0.f, 0.f, 0.f, 0.f};
        if (t > 0) {
            if (tid == 0) {
                while (__hip_atomic_load(&mycnt[t - 1], __ATOMIC_ACQUIRE,
                                         __HIP_MEMORY_SCOPE_AGENT) < 16u) { }
            }
            __syncthreads();

            int par = (t - 1) & 1;
            const short* hh = hb_hi + ((size_t)par * NB + b0 + fr) * HF + fkq * 8;
            const short* hl = hb_lo + ((size_t)par * NB + b0 + fr) * HF + fkq * 8;

            f32x4 a0 = {0.f,0.f,0.f,0.f}, a1 = a0, a2 = a0, a3 = a0, a4 = a0, a5 = a0;
            #pragma unroll
            for (int kt = 0; kt < 32; ++kt) {
                s16x8 ah = *(const s16x8*)(hh + kt * 32);
                s16x8 al = *(const s16x8*)(hl + kt * 32);
                if (kt & 1) {
                    a1 = mfma16(ah, wh[kt], a1);
                    a3 = mfma16(ah, wl[kt], a3);
                    a5 = mfma16(al, wh[kt], a5);
                } else {
                    a0 = mfma16(ah, wh[kt], a0);
                    a2 = mfma16(ah, wl[kt], a2);
                    a4 = mfma16(al, wh[kt], a4);
                }
            }
            sum = (a0 + a1) + ((a2 + a3) + (a4 + a5));
        }

        int par_w = t & 1;
        #pragma unroll
        for (int i = 0; i < 4; ++i) {
            int r = b0 + fkq * 4 + i;
            float p = ux[i] + sum[i] + wb;
            p = fminf(fmaxf(p, -12.f), 12.f);
            float e2 = __expf(2.f * p);
            float h  = (e2 - 1.f) / (e2 + 1.f);
            out[((size_t)r * SEQ + t) * HF + j] = h;
            if (t == SEQ - 1)
                out[(size_t)NB * SEQ * HF + (size_t)r * HF + j] = h;
            short hh_, hl_;
            bf16_split(h, hh_, hl_);
            hb_hi[((size_t)par_w * NB + r) * HF + j] = hh_;
            hb_lo[((size_t)par_w * NB + r) * HF + j] = hl_;
        }

        __syncthreads();  // drains all waves' stores (vmcnt(0) before s_barrier)
        if (tid == 0) {
            __hip_atomic_fetch_add(&mycnt[t], 1u, __ATOMIC_RELEASE,
                                   __HIP_MEMORY_SCOPE_AGENT);
        }
    }
}

extern "C" void kernel_launch(void* const* d_in, const int* in_sizes, int n_in,
                              void* d_out, int out_size, void* d_ws, size_t ws_size,
                              hipStream_t stream) {
    const float* X  = (const float*)d_in[0];   // input_emb [64,512,1024]
    const float* Ww = (const float*)d_in[1];   // W_w [1024,1024]
    const float* Wb = (const float*)d_in[2];   // W_b [1024]
    const float* Uw = (const float*)d_in[3];   // U_w [1024,1024]
    const float* Ub = (const float*)d_in[4];   // U_b [1024]
    float* out = (float*)d_out;

    unsigned int* cnt = (unsigned int*)d_ws;                       // 4*512*4 = 8 KB
    short* hb_hi = (short*)((char*)d_ws + 8192);                   // 2*64*1024*2 = 256 KB
    short* hb_lo = (short*)((char*)d_ws + 8192 + 2 * NB * HF * sizeof(short));

    hipMemsetAsync(d_ws, 0, 8192, stream);
    ux_gemm<<<dim3(2048), dim3(256), 0, stream>>>(X, Uw, Ub, out);
    rnn_scan<<<dim3(64), dim3(256), 0, stream>>>(Ww, Wb, out, hb_hi, hb_lo, cnt);
}

// Round 3
// 3389.911 us; speedup vs baseline: 2.1748x; 2.1748x over previous
//
#include <hip/hip_runtime.h>
#include <hip/hip_bf16.h>

#define SEQ 512
#define NB  64
#define HF  1024

typedef float f32x4 __attribute__((ext_vector_type(4)));
typedef short s16x8 __attribute__((ext_vector_type(8)));
typedef short s16x4 __attribute__((ext_vector_type(4)));
typedef unsigned long long u64;

__device__ __forceinline__ unsigned short bf16_rne(float f) {
    unsigned u = __builtin_bit_cast(unsigned, f);
    u += 0x7FFFu + ((u >> 16) & 1u);
    return (unsigned short)(u >> 16);
}

// split f = hi + lo (hi = truncated bf16, lo = rne bf16 of exact remainder)
__device__ __forceinline__ void bf16_split(float f, short& hi, short& lo) {
    unsigned u = __builtin_bit_cast(unsigned, f);
    hi = (short)(u >> 16);
    float fh = __builtin_bit_cast(float, u & 0xFFFF0000u);
    lo = (short)bf16_rne(f - fh);
}

__device__ __forceinline__ f32x4 mfma16(s16x8 a, s16x8 b, f32x4 c) {
    return __builtin_amdgcn_mfma_f32_16x16x32_bf16(a, b, c, 0, 0, 0);
}

// ---------------------------------------------------------------------------
// Phase 1: Ux = X @ U^T + U_b   (written into d_out, layout [B,S,H] = [32768,1024])
// 128x128 tiles, K-step 32, split-bf16 (3-term) MFMA.  (unchanged from R2)
// ---------------------------------------------------------------------------
__global__ __launch_bounds__(256, 2) void ux_gemm(const float* __restrict__ X,
                                                  const float* __restrict__ U,
                                                  const float* __restrict__ Ubias,
                                                  float* __restrict__ out) {
    __shared__ short Ah[128][40], Al[128][40], Bh[128][40], Bl[128][40];

    int bid = blockIdx.x;                    // 2048 = 256 m-tiles * 8 n-tiles
    int swz = (bid & 7) * 256 + (bid >> 3);  // XCD-contiguous chunks (2048 % 8 == 0)
    int tm = swz & 255;
    int tn = swz >> 8;

    int tid  = threadIdx.x;
    int lrow = tid >> 3;           // 0..31
    int lcol = (tid & 7) << 2;     // 0,4,..,28

    int wave = tid >> 6, lane = tid & 63;
    int wr = (wave >> 1) << 6;     // wave row offset (0/64)
    int wc = (wave & 1) << 6;      // wave col offset (0/64)
    int fr = lane & 15, fkq = lane >> 4;

    const float* Xb = X + (size_t)tm * 128 * HF;
    const float* Ub = U + (size_t)tn * 128 * HF;

    f32x4 acc[4][4];
    #pragma unroll
    for (int mi = 0; mi < 4; ++mi)
        #pragma unroll
        for (int ni = 0; ni < 4; ++ni)
            acc[mi][ni] = f32x4{0.f, 0.f, 0.f, 0.f};

    for (int kt = 0; kt < HF; kt += 32) {
        __syncthreads();
        #pragma unroll
        for (int p = 0; p < 4; ++p) {
            int r = lrow + (p << 5);
            f32x4 xv = *(const f32x4*)(Xb + (size_t)r * HF + kt + lcol);
            f32x4 uv = *(const f32x4*)(Ub + (size_t)r * HF + kt + lcol);
            s16x4 xh, xl, uh, ul;
            #pragma unroll
            for (int e = 0; e < 4; ++e) {
                short h_, l_;
                bf16_split(xv[e], h_, l_); xh[e] = h_; xl[e] = l_;
                bf16_split(uv[e], h_, l_); uh[e] = h_; ul[e] = l_;
            }
            *(s16x4*)&Ah[r][lcol] = xh;
            *(s16x4*)&Al[r][lcol] = xl;
            *(s16x4*)&Bh[r][lcol] = uh;
            *(s16x4*)&Bl[r][lcol] = ul;
        }
        __syncthreads();

        s16x8 afh[4], afl[4], bfh[4], bfl[4];
        #pragma unroll
        for (int mi = 0; mi < 4; ++mi) {
            afh[mi] = *(const s16x8*)&Ah[wr + mi * 16 + fr][fkq * 8];
            afl[mi] = *(const s16x8*)&Al[wr + mi * 16 + fr][fkq * 8];
            bfh[mi] = *(const s16x8*)&Bh[wc + mi * 16 + fr][fkq * 8];
            bfl[mi] = *(const s16x8*)&Bl[wc + mi * 16 + fr][fkq * 8];
        }
        #pragma unroll
        for (int mi = 0; mi < 4; ++mi)
            #pragma unroll
            for (int ni = 0; ni < 4; ++ni)
                acc[mi][ni] = mfma16(afh[mi], bfh[ni], acc[mi][ni]);
        #pragma unroll
        for (int mi = 0; mi < 4; ++mi)
            #pragma unroll
            for (int ni = 0; ni < 4; ++ni)
                acc[mi][ni] = mfma16(afh[mi], bfl[ni], acc[mi][ni]);
        #pragma unroll
        for (int mi = 0; mi < 4; ++mi)
            #pragma unroll
            for (int ni = 0; ni < 4; ++ni)
                acc[mi][ni] = mfma16(afl[mi], bfh[ni], acc[mi][ni]);
    }

    // epilogue: C/D layout col = lane&15, row = (lane>>4)*4 + i  [m89]
    #pragma unroll
    for (int ni = 0; ni < 4; ++ni) {
        int col = tn * 128 + wc + ni * 16 + fr;
        float ub = Ubias[col];
        #pragma unroll
        for (int mi = 0; mi < 4; ++mi) {
            #pragma unroll
            for (int i = 0; i < 4; ++i) {
                int row = tm * 128 + wr + mi * 16 + fkq * 4 + i;
                out[(size_t)row * HF + col] = acc[mi][ni][i] + ub;
            }
        }
    }
}

// ---------------------------------------------------------------------------
// Phase 2: 512 sequential steps  h = tanh(Ux_t + h@W^T + W_b)
// 64 persistent WGs (4 batch-tiles x 16 WGs), W slice resident in VGPRs.
// Sync redesign vs R2: per-WG flag STORES (relaxed, agent/sc1 -> LLC) instead
// of serialized release-RMWs on one counter; h exchanged via L2-bypassing
// relaxed atomic stores/loads (LLC is the serialization point) -> no wbl2 /
// no cache invalidates anywhere in the loop. h tile staged LLC->LDS once per
// WG (cooperative, XOR-swizzled vs 16-way bank conflict), 4 waves read frags
// from LDS.
// ---------------------------------------------------------------------------
__global__ __launch_bounds__(256, 1) void rnn_scan(const float* __restrict__ Ww,
                                                   const float* __restrict__ Wb,
                                                   float* __restrict__ out,
                                                   short* __restrict__ hb_hi,
                                                   short* __restrict__ hb_lo,
                                                   unsigned int* __restrict__ flags) {
    __shared__ short Hh[16][1024];   // 32 KB  (swizzled: byte ^= (row&7)<<4)
    __shared__ short Hl[16][1024];   // 32 KB

    int bid   = blockIdx.x;        // 64
    int btile = bid >> 4;          // 0..3  (16 batches each)
    int wgidx = bid & 15;          // this WG's slot in its sync group
    int tid   = threadIdx.x;
    int wave  = tid >> 6, lane = tid & 63;
    int j0    = (wgidx * 4 + wave) << 4;        // output col slice base
    int fr    = lane & 15, fkq = lane >> 4;
    int j     = j0 + fr;           // this lane's output column
    int b0    = btile << 4;
    int xr    = (fr & 7) << 4;     // LDS read swizzle for this lane

    // --- prologue: W fragments (rows j of W_w), split hi/lo, held in VGPRs ---
    s16x8 wh[32], wl[32];
    {
        const float* wp = Ww + (size_t)j * HF + fkq * 8;
        #pragma unroll
        for (int kt = 0; kt < 32; ++kt) {
            f32x4 a = *(const f32x4*)(wp + kt * 32);
            f32x4 b = *(const f32x4*)(wp + kt * 32 + 4);
            s16x8 hi, lo;
            #pragma unroll
            for (int e = 0; e < 4; ++e) {
                short h_, l_;
                bf16_split(a[e], h_, l_); hi[e]     = h_; lo[e]     = l_;
                bf16_split(b[e], h_, l_); hi[e + 4] = h_; lo[e + 4] = l_;
            }
            wh[kt] = hi; wl[kt] = lo;
        }
    }
    float wb = Wb[j];

    unsigned int* grp_flags = flags + btile * 16;   // 16 u32 in one 64B line

    #pragma unroll 1
    for (int t = 0; t < SEQ; ++t) {
        // issue Ux loads early (normal cached loads; L2 is never invalidated)
        float ux[4];
        #pragma unroll
        for (int i = 0; i < 4; ++i) {
            int r = b0 + fkq * 4 + i;
            ux[i] = out[((size_t)r * SEQ + t) * HF + j];
        }

        f32x4 sum = {0.f, 0.f, 0.f, 0.f};
        if (t > 0) {
            // --- wave-parallel spin: wait for all 16 WGs of group at step t ---
            unsigned int v;
            do {
                v = (lane < 16)
                    ? __hip_atomic_load(&grp_flags[lane], __ATOMIC_RELAXED,
                                        __HIP_MEMORY_SCOPE_AGENT)
                    : 0xFFFFFFFFu;
            } while (!__all(v >= (unsigned int)t));

            // --- cooperative stage: h tile (16 x 1024, hi+lo) LLC -> LDS ---
            int par = (t - 1) & 1;
            const u64* sh = (const u64*)(hb_hi + ((size_t)par * NB + b0) * HF);
            const u64* sl = (const u64*)(hb_lo + ((size_t)par * NB + b0) * HF);
            #pragma unroll
            for (int k = 0; k < 8; ++k) {
                int c   = (k << 8) + tid;            // 16B-chunk id, 0..2047
                int row = c >> 7;
                int bc  = (c & 127) << 4;
                int dst = (row << 11) + (bc ^ ((row & 7) << 4));
                u64 a0 = __hip_atomic_load(sh + c * 2,     __ATOMIC_RELAXED,
                                           __HIP_MEMORY_SCOPE_AGENT);
                u64 a1 = __hip_atomic_load(sh + c * 2 + 1, __ATOMIC_RELAXED,
                                           __HIP_MEMORY_SCOPE_AGENT);
                u64 b0_ = __hip_atomic_load(sl + c * 2,     __ATOMIC_RELAXED,
                                            __HIP_MEMORY_SCOPE_AGENT);
                u64 b1_ = __hip_atomic_load(sl + c * 2 + 1, __ATOMIC_RELAXED,
                                            __HIP_MEMORY_SCOPE_AGENT);
                *(u64*)((char*)Hh + dst)     = a0;
                *(u64*)((char*)Hh + dst + 8) = a1;
                *(u64*)((char*)Hl + dst)     = b0_;
                *(u64*)((char*)Hl + dst + 8) = b1_;
            }
            __syncthreads();

            // --- frags from LDS (swizzled) + 96 MFMA, 6 acc chains ---
            f32x4 a0 = {0.f,0.f,0.f,0.f}, a1 = a0, a2 = a0, a3 = a0, a4 = a0, a5 = a0;
            #pragma unroll
            for (int kt = 0; kt < 32; ++kt) {
                int boff = (fkq * 16 + (kt << 6)) ^ xr;
                s16x8 ah = *(const s16x8*)((const char*)Hh + (fr << 11) + boff);
                s16x8 al = *(const s16x8*)((const char*)Hl + (fr << 11) + boff);
                if (kt & 1) {
                    a1 = mfma16(ah, wh[kt], a1);
                    a3 = mfma16(ah, wl[kt], a3);
                    a5 = mfma16(al, wh[kt], a5);
                } else {
                    a0 = mfma16(ah, wh[kt], a0);
                    a2 = mfma16(ah, wl[kt], a2);
                    a4 = mfma16(al, wh[kt], a4);
                }
            }
            sum = (a0 + a1) + ((a2 + a3) + (a4 + a5));
        }

        // --- epilogue: tanh, store out (normal) + h (bypass to LLC) ---
        int par_w = t & 1;
        #pragma unroll
        for (int i = 0; i < 4; ++i) {
            int r = b0 + fkq * 4 + i;
            float p = ux[i] + sum[i] + wb;
            p = fminf(fmaxf(p, -12.f), 12.f);
            float e2 = __expf(2.f * p);
            float h  = (e2 - 1.f) / (e2 + 1.f);
            out[((size_t)r * SEQ + t) * HF + j] = h;
            if (t == SEQ - 1)
                out[(size_t)NB * SEQ * HF + (size_t)r * HF + j] = h;
            short hh_, hl_;
            bf16_split(h, hh_, hl_);
            size_t hb = ((size_t)par_w * NB + r) * HF + j;
            __hip_atomic_store(&hb_hi[hb], hh_, __ATOMIC_RELAXED,
                               __HIP_MEMORY_SCOPE_AGENT);
            __hip_atomic_store(&hb_lo[hb], hl_, __ATOMIC_RELAXED,
                               __HIP_MEMORY_SCOPE_AGENT);
        }

        // drain this wave's stores (sc1 stores retire when accepted at LLC),
        // then barrier covers all waves; flag store is ordered after both.
        asm volatile("s_waitcnt vmcnt(0)" ::: "memory");
        __syncthreads();
        if (tid == 0) {
            __hip_atomic_store(&grp_flags[wgidx], (unsigned int)(t + 1),
                               __ATOMIC_RELAXED, __HIP_MEMORY_SCOPE_AGENT);
        }
    }
}

extern "C" void kernel_launch(void* const* d_in, const int* in_sizes, int n_in,
                              void* d_out, int out_size, void* d_ws, size_t ws_size,
                              hipStream_t stream) {
    const float* X  = (const float*)d_in[0];   // input_emb [64,512,1024]
    const float* Ww = (const float*)d_in[1];   // W_w [1024,1024]
    const float* Wb = (const float*)d_in[2];   // W_b [1024]
    const float* Uw = (const float*)d_in[3];   // U_w [1024,1024]
    const float* Ub = (const float*)d_in[4];   // U_b [1024]
    float* out = (float*)d_out;

    unsigned int* flags = (unsigned int*)d_ws;                     // 4*16 u32 (memset)
    short* hb_hi = (short*)((char*)d_ws + 8192);                   // 2*64*1024*2 = 256 KB
    short* hb_lo = (short*)((char*)d_ws + 8192 + 2 * NB * HF * sizeof(short));

    hipMemsetAsync(d_ws, 0, 8192, stream);
    ux_gemm<<<dim3(2048), dim3(256), 0, stream>>>(X, Uw, Ub, out);
    rnn_scan<<<dim3(64), dim3(256), 0, stream>>>(Ww, Wb, out, hb_hi, hb_lo, flags);
}

// Round 4
// 2523.861 us; speedup vs baseline: 2.9210x; 1.3431x over previous
//
#include <hip/hip_runtime.h>
#include <hip/hip_bf16.h>

#define SEQ 512
#define NB  64
#define HF  1024

typedef float f32x4 __attribute__((ext_vector_type(4)));
typedef short s16x8 __attribute__((ext_vector_type(8)));
typedef short s16x4 __attribute__((ext_vector_type(4)));
typedef _Float16 f16x8 __attribute__((ext_vector_type(8)));
typedef unsigned long long u64;

__device__ __forceinline__ unsigned short bf16_rne(float f) {
    unsigned u = __builtin_bit_cast(unsigned, f);
    u += 0x7FFFu + ((u >> 16) & 1u);
    return (unsigned short)(u >> 16);
}

// split f = hi + lo (hi = truncated bf16, lo = rne bf16 of exact remainder)
__device__ __forceinline__ void bf16_split(float f, short& hi, short& lo) {
    unsigned u = __builtin_bit_cast(unsigned, f);
    hi = (short)(u >> 16);
    float fh = __builtin_bit_cast(float, u & 0xFFFF0000u);
    lo = (short)bf16_rne(f - fh);
}

__device__ __forceinline__ f32x4 mfma16(s16x8 a, s16x8 b, f32x4 c) {
    return __builtin_amdgcn_mfma_f32_16x16x32_bf16(a, b, c, 0, 0, 0);
}

__device__ __forceinline__ f32x4 mfma16f(f16x8 a, f16x8 b, f32x4 c) {
    return __builtin_amdgcn_mfma_f32_16x16x32_f16(a, b, c, 0, 0, 0);
}

// ---------------------------------------------------------------------------
// Phase 1: Ux = X @ U^T + U_b   (written into d_out, layout [B,S,H] = [32768,1024])
// 128x128 tiles, K-step 32, split-bf16 (3-term) MFMA.  (unchanged — passed R2/R3)
// ---------------------------------------------------------------------------
__global__ __launch_bounds__(256, 2) void ux_gemm(const float* __restrict__ X,
                                                  const float* __restrict__ U,
                                                  const float* __restrict__ Ubias,
                                                  float* __restrict__ out) {
    __shared__ short Ah[128][40], Al[128][40], Bh[128][40], Bl[128][40];

    int bid = blockIdx.x;                    // 2048 = 256 m-tiles * 8 n-tiles
    int swz = (bid & 7) * 256 + (bid >> 3);  // XCD-contiguous chunks (2048 % 8 == 0)
    int tm = swz & 255;
    int tn = swz >> 8;

    int tid  = threadIdx.x;
    int lrow = tid >> 3;           // 0..31
    int lcol = (tid & 7) << 2;     // 0,4,..,28

    int wave = tid >> 6, lane = tid & 63;
    int wr = (wave >> 1) << 6;     // wave row offset (0/64)
    int wc = (wave & 1) << 6;      // wave col offset (0/64)
    int fr = lane & 15, fkq = lane >> 4;

    const float* Xb = X + (size_t)tm * 128 * HF;
    const float* Ub = U + (size_t)tn * 128 * HF;

    f32x4 acc[4][4];
    #pragma unroll
    for (int mi = 0; mi < 4; ++mi)
        #pragma unroll
        for (int ni = 0; ni < 4; ++ni)
            acc[mi][ni] = f32x4{0.f, 0.f, 0.f, 0.f};

    for (int kt = 0; kt < HF; kt += 32) {
        __syncthreads();
        #pragma unroll
        for (int p = 0; p < 4; ++p) {
            int r = lrow + (p << 5);
            f32x4 xv = *(const f32x4*)(Xb + (size_t)r * HF + kt + lcol);
            f32x4 uv = *(const f32x4*)(Ub + (size_t)r * HF + kt + lcol);
            s16x4 xh, xl, uh, ul;
            #pragma unroll
            for (int e = 0; e < 4; ++e) {
                short h_, l_;
                bf16_split(xv[e], h_, l_); xh[e] = h_; xl[e] = l_;
                bf16_split(uv[e], h_, l_); uh[e] = h_; ul[e] = l_;
            }
            *(s16x4*)&Ah[r][lcol] = xh;
            *(s16x4*)&Al[r][lcol] = xl;
            *(s16x4*)&Bh[r][lcol] = uh;
            *(s16x4*)&Bl[r][lcol] = ul;
        }
        __syncthreads();

        s16x8 afh[4], afl[4], bfh[4], bfl[4];
        #pragma unroll
        for (int mi = 0; mi < 4; ++mi) {
            afh[mi] = *(const s16x8*)&Ah[wr + mi * 16 + fr][fkq * 8];
            afl[mi] = *(const s16x8*)&Al[wr + mi * 16 + fr][fkq * 8];
            bfh[mi] = *(const s16x8*)&Bh[wc + mi * 16 + fr][fkq * 8];
            bfl[mi] = *(const s16x8*)&Bl[wc + mi * 16 + fr][fkq * 8];
        }
        #pragma unroll
        for (int mi = 0; mi < 4; ++mi)
            #pragma unroll
            for (int ni = 0; ni < 4; ++ni)
                acc[mi][ni] = mfma16(afh[mi], bfh[ni], acc[mi][ni]);
        #pragma unroll
        for (int mi = 0; mi < 4; ++mi)
            #pragma unroll
            for (int ni = 0; ni < 4; ++ni)
                acc[mi][ni] = mfma16(afh[mi], bfl[ni], acc[mi][ni]);
        #pragma unroll
        for (int mi = 0; mi < 4; ++mi)
            #pragma unroll
            for (int ni = 0; ni < 4; ++ni)
                acc[mi][ni] = mfma16(afl[mi], bfh[ni], acc[mi][ni]);
    }

    // epilogue: C/D layout col = lane&15, row = (lane>>4)*4 + i  [m89]
    #pragma unroll
    for (int ni = 0; ni < 4; ++ni) {
        int col = tn * 128 + wc + ni * 16 + fr;
        float ub = Ubias[col];
        #pragma unroll
        for (int mi = 0; mi < 4; ++mi) {
            #pragma unroll
            for (int i = 0; i < 4; ++i) {
                int row = tm * 128 + wr + mi * 16 + fkq * 4 + i;
                out[(size_t)row * HF + col] = acc[mi][ni][i] + ub;
            }
        }
    }
}

// ---------------------------------------------------------------------------
// Phase 2: 512 sequential steps  h = tanh(Ux_t + h@W^T + W_b)
// v4: 32 WGs = 4 batch-groups x 8 WGs(512thr, 8 waves x 16 cols).
//   - W single f16 in VGPRs (128 regs/lane) -> no spill; 32 MFMA/step.
//   - h exchanged as f16 via LLC (sc1 relaxed atomics), payload halved.
//   - hb stored PRE-SWIZZLED (16B-granule XOR by (localrow&7)<<4) so the
//     LLC->LDS stage is a pure linear coalesced copy; readers XOR.
//   - per-WG flag stores (relaxed sc1) + wave-parallel poll, as in R3.
// ---------------------------------------------------------------------------
__global__ __launch_bounds__(512, 2) void rnn_scan(const float* __restrict__ Ww,
                                                   const float* __restrict__ Wb,
                                                   float* __restrict__ out,
                                                   _Float16* __restrict__ hb,
                                                   unsigned int* __restrict__ flags) {
    __shared__ _Float16 Hs[16 * HF];   // 32 KB: row=local batch, 2048B/row, swizzled

    int bid   = blockIdx.x;        // 32
    int btile = bid >> 3;          // 0..3  (16 batches each)
    int wgidx = bid & 7;           // slot in sync group
    int tid   = threadIdx.x;       // 0..511
    int wave  = tid >> 6, lane = tid & 63;
    int fr    = lane & 15, fkq = lane >> 4;
    int j     = ((wgidx * 8 + wave) << 4) + fr;   // this lane's output column
    int b0    = btile << 4;
    int xr    = (fr & 7) << 4;     // LDS read swizzle

    // --- prologue: W row j as single f16 frags, 128 VGPRs ---
    f16x8 wf[32];
    {
        const float* wp = Ww + (size_t)j * HF + fkq * 8;
        #pragma unroll
        for (int kt = 0; kt < 32; ++kt) {
            f32x4 a = *(const f32x4*)(wp + kt * 32);
            f32x4 b = *(const f32x4*)(wp + kt * 32 + 4);
            f16x8 w;
            #pragma unroll
            for (int e = 0; e < 4; ++e) {
                w[e]     = (_Float16)a[e];
                w[e + 4] = (_Float16)b[e];
            }
            wf[kt] = w;
        }
    }
    float wb = Wb[j];

    unsigned int* grp_flags = flags + btile * 16;   // 8 used, 64B line per group

    #pragma unroll 1
    for (int t = 0; t < SEQ; ++t) {
        // issue Ux loads early (latency hides under spin+stage+MFMA)
        float ux[4];
        #pragma unroll
        for (int i = 0; i < 4; ++i) {
            int r = b0 + fkq * 4 + i;
            ux[i] = out[((size_t)r * SEQ + t) * HF + j];
        }

        f32x4 sum = {0.f, 0.f, 0.f, 0.f};
        if (t > 0) {
            // wait for all 8 WGs of this group to finish step t-1
            unsigned int v;
            do {
                v = (lane < 8)
                    ? __hip_atomic_load(&grp_flags[lane], __ATOMIC_RELAXED,
                                        __HIP_MEMORY_SCOPE_AGENT)
                    : 0xFFFFFFFFu;
            } while (!__all(v >= (unsigned int)t));

            // linear coalesced stage: 32KB group h slice (pre-swizzled) -> LDS
            int par = (t - 1) & 1;
            const u64* src = (const u64*)(hb + ((size_t)par * NB + b0) * HF);
            #pragma unroll
            for (int k = 0; k < 4; ++k) {
                int c = (k << 9) + tid;            // 16B chunk id, 0..2047
                u64 a0 = __hip_atomic_load(src + c * 2,     __ATOMIC_RELAXED,
                                           __HIP_MEMORY_SCOPE_AGENT);
                u64 a1 = __hip_atomic_load(src + c * 2 + 1, __ATOMIC_RELAXED,
                                           __HIP_MEMORY_SCOPE_AGENT);
                *(u64*)((char*)Hs + c * 16)     = a0;
                *(u64*)((char*)Hs + c * 16 + 8) = a1;
            }
            __syncthreads();

            // 32 x mfma_f32_16x16x32_f16, 4 acc chains
            f32x4 a0 = {0.f,0.f,0.f,0.f}, a1 = a0, a2 = a0, a3 = a0;
            int rbase = fr << 11;
            #pragma unroll
            for (int kt = 0; kt < 32; ++kt) {
                int boff = (fkq * 16 + (kt << 6)) ^ xr;
                f16x8 hv = *(const f16x8*)((const char*)Hs + rbase + boff);
                if ((kt & 3) == 0)      a0 = mfma16f(hv, wf[kt], a0);
                else if ((kt & 3) == 1) a1 = mfma16f(hv, wf[kt], a1);
                else if ((kt & 3) == 2) a2 = mfma16f(hv, wf[kt], a2);
                else                    a3 = mfma16f(hv, wf[kt], a3);
            }
            sum = (a0 + a1) + (a2 + a3);
        }

        // epilogue: tanh, store out (f32) + h (f16, pre-swizzled, sc1 -> LLC)
        int par_w = t & 1;
        char* hrow = (char*)(hb + (size_t)par_w * NB * HF);
        #pragma unroll
        for (int i = 0; i < 4; ++i) {
            int lr = fkq * 4 + i;          // local row 0..15
            int r  = b0 + lr;
            float p = ux[i] + sum[i] + wb;
            p = fminf(fmaxf(p, -12.f), 12.f);
            float e2 = __expf(2.f * p);
            float h  = (e2 - 1.f) / (e2 + 1.f);
            out[((size_t)r * SEQ + t) * HF + j] = h;
            if (t == SEQ - 1)
                out[(size_t)NB * SEQ * HF + (size_t)r * HF + j] = h;
            _Float16 hf = (_Float16)h;
            size_t boff = (size_t)r * 2048 + (size_t)((j * 2) ^ ((lr & 7) << 4));
            __hip_atomic_store((short*)(hrow + boff),
                               __builtin_bit_cast(short, hf),
                               __ATOMIC_RELAXED, __HIP_MEMORY_SCOPE_AGENT);
        }

        // drain h stores to LLC, barrier all waves (also fences LDS reads
        // vs next iteration's staging), then publish flag
        asm volatile("s_waitcnt vmcnt(0)" ::: "memory");
        __syncthreads();
        if (tid == 0) {
            __hip_atomic_store(&grp_flags[wgidx], (unsigned int)(t + 1),
                               __ATOMIC_RELAXED, __HIP_MEMORY_SCOPE_AGENT);
        }
    }
}

extern "C" void kernel_launch(void* const* d_in, const int* in_sizes, int n_in,
                              void* d_out, int out_size, void* d_ws, size_t ws_size,
                              hipStream_t stream) {
    const float* X  = (const float*)d_in[0];   // input_emb [64,512,1024]
    const float* Ww = (const float*)d_in[1];   // W_w [1024,1024]
    const float* Wb = (const float*)d_in[2];   // W_b [1024]
    const float* Uw = (const float*)d_in[3];   // U_w [1024,1024]
    const float* Ub = (const float*)d_in[4];   // U_b [1024]
    float* out = (float*)d_out;

    unsigned int* flags = (unsigned int*)d_ws;              // 4 groups x 16 u32
    _Float16* hb = (_Float16*)((char*)d_ws + 8192);         // 2*64*1024 f16 = 256 KB

    hipMemsetAsync(d_ws, 0, 8192, stream);
    ux_gemm<<<dim3(2048), dim3(256), 0, stream>>>(X, Uw, Ub, out);
    rnn_scan<<<dim3(32), dim3(512), 0, stream>>>(Ww, Wb, out, hb, flags);
}